// Round 16
// baseline (177.363 us; speedup 1.0000x reference)
//
#include <hip/hip_runtime.h>
#include <stdint.h>

typedef unsigned short u16;
typedef __bf16 bf16x8 __attribute__((ext_vector_type(8)));
typedef float f32x4 __attribute__((ext_vector_type(4)));

// Problem constants: T=1024, B=32, E=512, HEADS=8, KEYD=16, HEAD=64, MEM_SLOTS=8, TOPK=3

__device__ __forceinline__ u16 f2b(float f) {
  union { __bf16 h; u16 u; } v; v.h = (__bf16)f; return v.u;
}
__device__ __forceinline__ float b2f(u16 h) {
  union { uint32_t u; float f; } v; v.u = ((uint32_t)h) << 16; return v.f;
}
__device__ __forceinline__ void gload_lds16(const void* g, void* l) {
  __builtin_amdgcn_global_load_lds(
      (const __attribute__((address_space(1))) unsigned int*)g,
      (__attribute__((address_space(3))) unsigned int*)l, 16, 0, 0);
}

// ---------------- fused prep: converts + tanh(mem) + bfull[0:512] + keyB; tail blocks: bias + qm ----------------
__global__ void k_prep(const float* __restrict__ W_in, u16* __restrict__ WxT,
                       const float* __restrict__ Wv, u16* __restrict__ WvT,
                       const float* __restrict__ mem, float* __restrict__ tm,
                       const float* __restrict__ b_in, float* __restrict__ bfull,
                       const float* __restrict__ Wk, const float* __restrict__ Wq,
                       u16* __restrict__ WkqTr, u16* __restrict__ WinB,
                       const float* __restrict__ W_mlp, u16* __restrict__ WmlpT,
                       const float* __restrict__ key, u16* __restrict__ keyB,
                       const float* __restrict__ bk, const float* __restrict__ bq,
                       float* __restrict__ qm) {
  __shared__ float sh_a[512];
  __shared__ float sh_p[2][128];
  const int tid = threadIdx.x;
  if (blockIdx.x < 13314) {
    int idx = blockIdx.x * 256 + tid;
    if (idx < 262144) {
      int k = idx >> 9, n = idx & 511;
      WxT[n * 512 + k] = f2b(W_in[idx]);
    } else if (idx < 524288) {
      int j = idx - 262144;
      int k = j >> 9, n = j & 511;
      WvT[n * 512 + k] = f2b(Wv[j]);
    } else if (idx < 655360) {
      int j = idx - 524288;
      tm[j] = tanhf(mem[j]);
    } else if (idx < 655872) {
      int j = idx - 655360;
      bfull[j] = b_in[j];
    } else if (idx < 786944) {
      int i = idx - 655872;                 // WkqTr[j][n] = Wkq[n][j]
      int j = i >> 9, n = i & 511;
      WkqTr[i] = f2b(j < 128 ? Wk[n * 128 + j] : Wq[n * 128 + j - 128]);
    } else if (idx < 1049088) {
      int i = idx - 786944;                 // WinB = W_in row-major bf16
      WinB[i] = f2b(W_in[i]);
    } else if (idx < 1311232) {
      int i = idx - 1049088;                // WmlpT[n][k] = W_mlp[k][n]
      int k = i >> 9, n = i & 511;
      WmlpT[n * 512 + k] = f2b(W_mlp[i]);
    } else {
      int i = idx - 1311232;                // keyB: (T,B,E) f32 -> (B*T,E) bf16, 8 elems
      int r = i >> 6, e8 = i & 63;
      int b = r >> 10, t = r & 1023;
      const float* src = key + ((size_t)(t * 32 + b) << 9) + e8 * 8;
      float4 lo = *(const float4*)src;
      float4 hi = *(const float4*)(src + 4);
      bf16x8 o;
      o[0] = (__bf16)lo.x; o[1] = (__bf16)lo.y; o[2] = (__bf16)lo.z; o[3] = (__bf16)lo.w;
      o[4] = (__bf16)hi.x; o[5] = (__bf16)hi.y; o[6] = (__bf16)hi.z; o[7] = (__bf16)hi.w;
      *(bf16x8*)(keyB + ((size_t)r << 9) + e8 * 8) = o;
    }
  } else {
    const int wb = blockIdx.x - 13314;     // 0 = bias, 1..256 = qm
    if (wb == 0) {
      // bfull[512+j] = b_in @ Wkq[:,j] + bkq[j]
      sh_a[tid] = b_in[tid];
      sh_a[256 + tid] = b_in[256 + tid];
      __syncthreads();
      const int j = tid;
      const float* W = (j < 128) ? (Wk + j) : (Wq + j - 128);
      float a = 0.f;
      #pragma unroll 8
      for (int n = 0; n < 512; ++n)
        a += sh_a[n] * W[(size_t)n * 128];
      bfull[512 + j] = a + ((j < 128) ? bk[j] : bq[j - 128]);
    } else {
      // qm[b,s,:] = memory[b,s,:] @ Wq + bq
      const int bs_ = wb - 1;              // 0..255
      const int b = bs_ >> 3, s = bs_ & 7;
      const int col = tid & 127, half = tid >> 7;
      *(float2*)&sh_a[tid * 2] = *(const float2*)&mem[(size_t)(b * 8 + s) * 512 + tid * 2];
      __syncthreads();
      float a = 0.f;
      const int e0 = half * 256;
      for (int e = 0; e < 256; ++e)
        a += sh_a[e0 + e] * Wq[(size_t)(e0 + e) * 128 + col];
      sh_p[half][col] = a;
      __syncthreads();
      if (tid < 128)
        qm[(size_t)(b * 8 + s) * 128 + tid] = sh_p[0][tid] + sh_p[1][tid] + bq[tid];
    }
  }
}

// ---------------- Wc^T via MFMA: C[j,e] = WkqTr[j,:] @ WinB[e,:]^T -> WxT rows 512-767 ----------------
__global__ __launch_bounds__(256) void gemm_wc(
    const u16* __restrict__ A, const u16* __restrict__ Bt, u16* __restrict__ WxT)
{
  __shared__ u16 As[128 * 32];
  __shared__ u16 Bs[128 * 32];
  const int tid = threadIdx.x;
  const int m0 = blockIdx.x * 128;
  const int n0 = blockIdx.y * 128;
  const int lane = tid & 63;
  const int wid = tid >> 6;
  const int wm = (wid >> 1) * 64;
  const int wn = (wid & 1) * 64;

  f32x4 acc[4][4];
  #pragma unroll
  for (int i = 0; i < 4; ++i)
    #pragma unroll
    for (int j = 0; j < 4; ++j) acc[i][j] = (f32x4){0.f, 0.f, 0.f, 0.f};

  for (int kt = 0; kt < 16; ++kt) {
    const int k0 = kt << 5;
    __syncthreads();
    #pragma unroll
    for (int c = 0; c < 2; ++c) {
      int o = c * 2048 + tid * 8;
      int row = o >> 5, ck = o & 31;
      gload_lds16(A + (size_t)(m0 + row) * 512 + k0 + ck, As + o);
      gload_lds16(Bt + (size_t)(n0 + row) * 512 + k0 + ck, Bs + o);
    }
    __syncthreads();
    const int r = lane & 15;
    const int kb = (lane >> 4) * 8;
    bf16x8 af[4], bfr[4];
    #pragma unroll
    for (int i = 0; i < 4; ++i) {
      af[i]  = *(const bf16x8*)(As + (wm + i * 16 + r) * 32 + kb);
      bfr[i] = *(const bf16x8*)(Bs + (wn + i * 16 + r) * 32 + kb);
    }
    #pragma unroll
    for (int i = 0; i < 4; ++i)
      #pragma unroll
      for (int j = 0; j < 4; ++j)
        acc[i][j] = __builtin_amdgcn_mfma_f32_16x16x32_bf16(af[i], bfr[j], acc[i][j], 0, 0, 0);
  }
  const int cl = lane & 15;
  const int rl = (lane >> 4) * 4;
  #pragma unroll
  for (int j = 0; j < 4; ++j) {
    const int col = n0 + wn + j * 16 + cl;
    #pragma unroll
    for (int i = 0; i < 4; ++i) {
      #pragma unroll
      for (int rr = 0; rr < 4; ++rr) {
        const int row = m0 + wm + i * 16 + rl + rr;
        WxT[(size_t)(512 + row) * 512 + col] = f2b(acc[i][j][rr]);
      }
    }
  }
}

// ---------------- fused GEMM: [x | kq] = keyB @ WxT^T + bfull  (M=32768, N=768, K=512) ----------------
__global__ __launch_bounds__(256) void gemm_xkq(
    const u16* __restrict__ keyB, const u16* __restrict__ Bt,
    const float* __restrict__ bias, u16* __restrict__ x, u16* __restrict__ kq)
{
  __shared__ u16 smem[16384];               // As[8192] | Bs[8192]; aliased as Cs[128*128]
  u16* As = smem;
  u16* Bs = smem + 8192;
  const int tid = threadIdx.x;
  const int bid = blockIdx.x;                     // 1536 blocks
  const int wgid = (bid & 7) * 192 + (bid >> 3);  // XCD swizzle (1536 % 8 == 0, bijective)
  const int m0 = (wgid / 6) * 128;
  const int n0 = (wgid % 6) * 128;
  const int lane = tid & 63;
  const int wid = tid >> 6;
  const int wm = (wid >> 1) * 64;
  const int wn = (wid & 1) * 64;

  f32x4 acc[4][4];
  #pragma unroll
  for (int i = 0; i < 4; ++i)
    #pragma unroll
    for (int j = 0; j < 4; ++j) acc[i][j] = (f32x4){0.f, 0.f, 0.f, 0.f};

  for (int kt = 0; kt < 8; ++kt) {
    const int k0 = kt << 6;
    __syncthreads();
    #pragma unroll
    for (int c = 0; c < 4; ++c) {
      const int q = c * 256 + tid;     // 16B chunk id, 0..1023
      const int row = q >> 3;          // 0..127
      const int c8 = q & 7;            // chunk slot within row
      const int lc = c8 ^ (row & 7);   // pre-swizzled global chunk
      gload_lds16(keyB + (size_t)(m0 + row) * 512 + k0 + lc * 8, As + q * 8);
      gload_lds16(Bt   + (size_t)(n0 + row) * 512 + k0 + lc * 8, Bs + q * 8);
    }
    __syncthreads();
    const int r = lane & 15;
    const int hi = lane >> 4;
    bf16x8 af[4][2], bfr[4][2];
    #pragma unroll
    for (int i = 0; i < 4; ++i) {
      const int ra = wm + i * 16 + r;
      const int rb = wn + i * 16 + r;
      #pragma unroll
      for (int kk = 0; kk < 2; ++kk) {
        af[i][kk]  = *(const bf16x8*)(As + ra * 64 + (((kk * 4 + hi)) ^ (ra & 7)) * 8);
        bfr[i][kk] = *(const bf16x8*)(Bs + rb * 64 + (((kk * 4 + hi)) ^ (rb & 7)) * 8);
      }
    }
    #pragma unroll
    for (int kk = 0; kk < 2; ++kk)
      #pragma unroll
      for (int i = 0; i < 4; ++i)
        #pragma unroll
        for (int j = 0; j < 4; ++j)
          acc[i][j] = __builtin_amdgcn_mfma_f32_16x16x32_bf16(af[i][kk], bfr[j][kk], acc[i][j], 0, 0, 0);
  }
  // epilogue: stage C tile in LDS, then coalesced uint4 stores (full 64B lines)
  __syncthreads();
  u16* Cs = smem;
  const int cl = lane & 15;
  const int rl = (lane >> 4) * 4;
  #pragma unroll
  for (int j = 0; j < 4; ++j) {
    const int lcol = wn + j * 16 + cl;
    const float bsv = bias[n0 + lcol];
    #pragma unroll
    for (int i = 0; i < 4; ++i)
      #pragma unroll
      for (int rr = 0; rr < 4; ++rr)
        Cs[(wm + i * 16 + rl + rr) * 128 + lcol] = f2b(acc[i][j][rr] + bsv);
  }
  __syncthreads();
  #pragma unroll
  for (int c = 0; c < 8; ++c) {
    const int chunk = c * 256 + tid;        // 2048 chunks of 8 u16
    const int row = chunk >> 4, c8 = chunk & 15;
    uint4 v = *(const uint4*)&Cs[row * 128 + c8 * 8];
    if (n0 < 512)
      *(uint4*)(x + (size_t)(m0 + row) * 512 + n0 + c8 * 8) = v;
    else
      *(uint4*)(kq + (size_t)(m0 + row) * 256 + (n0 - 512) + c8 * 8) = v;
  }
}

// ---------------- scores + top3 + softmax per (b,h,s), fused XW write ----------------
__global__ __launch_bounds__(256) void k_scores_topk(
    const float* __restrict__ qm, const u16* __restrict__ kq,
    const u16* __restrict__ x, float* __restrict__ p3, u16* __restrict__ XW)
{
  const int b = blockIdx.x, h = blockIdx.y, s = blockIdx.z;
  const int tid = threadIdx.x;
  __shared__ float swv[4];
  __shared__ int   swi[4];
  __shared__ float ssv[4];

  float q[16];
  const float* qp = qm + ((size_t)(b * 8 + s) * 128 + h * 16);
  #pragma unroll
  for (int d = 0; d < 16; ++d) q[d] = qp[d];

  float sc[4];
  #pragma unroll
  for (int j = 0; j < 4; ++j) {
    const int t = j * 256 + tid;
    const u16* kr = kq + ((size_t)(b * 1024 + t)) * 256 + h * 16;
    uint4 v0 = *(const uint4*)kr;
    uint4 v1 = *(const uint4*)(kr + 8);
    const u16* p0 = (const u16*)&v0;
    const u16* p1 = (const u16*)&v1;
    float a = 0.f;
    #pragma unroll
    for (int d = 0; d < 8; ++d) a += q[d] * b2f(p0[d]);
    #pragma unroll
    for (int d = 0; d < 8; ++d) a += q[8 + d] * b2f(p1[d]);
    sc[j] = a;
  }

  int   seli[3];
  float selv[3];
  float ssum = 0.f;
  #pragma unroll
  for (int pass = 0; pass < 3; ++pass) {
    float bv_ = -1e30f; int bi_ = 1 << 30;
    #pragma unroll
    for (int j = 0; j < 4; ++j) {
      const int t = j * 256 + tid;
      bool skip = false;
      for (int k = 0; k < pass; ++k) skip |= (t == seli[k]);
      float v = skip ? -1e30f : sc[j];
      if (v > bv_ || (v == bv_ && t < bi_)) { bv_ = v; bi_ = t; }
    }
    #pragma unroll
    for (int o = 32; o > 0; o >>= 1) {
      float ov = __shfl_xor(bv_, o);
      int   oi = __shfl_xor(bi_, o);
      if (ov > bv_ || (ov == bv_ && oi < bi_)) { bv_ = ov; bi_ = oi; }
    }
    __syncthreads();
    if ((tid & 63) == 0) { swv[tid >> 6] = bv_; swi[tid >> 6] = bi_; }
    __syncthreads();
    float wv = swv[0]; int wi = swi[0];
    #pragma unroll
    for (int w = 1; w < 4; ++w) {
      float ov = swv[w]; int oi = swi[w];
      if (ov > wv || (ov == wv && oi < wi)) { wv = ov; wi = oi; }
    }
    selv[pass] = wv; seli[pass] = wi;

    if (pass == 0) {
      float se = 0.f;
      #pragma unroll
      for (int j = 0; j < 4; ++j) se += __expf(sc[j] - wv);
      #pragma unroll
      for (int o = 32; o > 0; o >>= 1) se += __shfl_xor(se, o);
      __syncthreads();
      if ((tid & 63) == 0) ssv[tid >> 6] = se;
      __syncthreads();
      ssum = ssv[0] + ssv[1] + ssv[2] + ssv[3];
    }
  }

  const float m0v = selv[0];
  const float inv = 1.f / ssum;
  const float p0 = __expf(selv[0] - m0v) * inv;
  const float p1 = __expf(selv[1] - m0v) * inv;
  const float p2 = __expf(selv[2] - m0v) * inv;
  if (tid == 0) {
    const size_t base = (size_t)(b * 64 + h * 8 + s);
    p3[base * 4 + 0] = p0;
    p3[base * 4 + 1] = p1;
    p3[base * 4 + 2] = p2;
    p3[base * 4 + 3] = p0 + p1 + p2;
  }
  if (tid < 64) {
    const u16* xb = x + ((size_t)b << 19) + tid * 8;
    uint4 a0 = *(const uint4*)(xb + ((size_t)seli[0] << 9));
    uint4 a1 = *(const uint4*)(xb + ((size_t)seli[1] << 9));
    uint4 a2 = *(const uint4*)(xb + ((size_t)seli[2] << 9));
    const u16* e0 = (const u16*)&a0;
    const u16* e1 = (const u16*)&a1;
    const u16* e2 = (const u16*)&a2;
    u16 ov[8];
    #pragma unroll
    for (int k = 0; k < 8; ++k)
      ov[k] = f2b(p0 * b2f(e0[k]) + p1 * b2f(e1[k]) + p2 * b2f(e2[k]));
    *(uint4*)(XW + (size_t)h * 131072 + (size_t)(b * 8 + s) * 512 + tid * 8) = *(const uint4*)ov;
  }
}

// ---------------- merged: blocks 0-15 = att per-head MFMA GEMM, 16-271 = gi partials ----------------
__global__ __launch_bounds__(256) void k_attgi(
    const u16* __restrict__ XW, const u16* __restrict__ WvT,
    const float* __restrict__ p3, const float* __restrict__ bvv,
    float* __restrict__ att,
    const u16* __restrict__ x, const float* __restrict__ w_rep,
    float* __restrict__ gpart)
{
  __shared__ u16 As[128 * 32];
  __shared__ u16 Bs[64 * 32];
  __shared__ float ps[4][512];
  const int bid = blockIdx.x;
  const int tid = threadIdx.x;
  if (bid < 16) {
    const int h = bid >> 1;
    const int m0 = (bid & 1) * 128;
    const int lane = tid & 63;
    const int wid = tid >> 6;
    const int wm = wid * 32;
    const u16* A = XW + (size_t)h * 131072;
    const u16* Bh = WvT + (size_t)h * 64 * 512;

    f32x4 acc[2][4];
    #pragma unroll
    for (int i = 0; i < 2; ++i)
      #pragma unroll
      for (int j = 0; j < 4; ++j) acc[i][j] = (f32x4){0.f, 0.f, 0.f, 0.f};

    for (int kt = 0; kt < 16; ++kt) {
      const int k0 = kt << 5;
      __syncthreads();
      #pragma unroll
      for (int c = 0; c < 2; ++c) {
        int o = c * 2048 + tid * 8;
        int row = o >> 5, ck = o & 31;
        gload_lds16(A + (size_t)(m0 + row) * 512 + k0 + ck, As + o);
      }
      {
        int row = tid >> 2, ck = (tid & 3) * 8;
        gload_lds16(Bh + (size_t)row * 512 + k0 + ck, Bs + row * 32 + ck);
      }
      __syncthreads();
      const int r = lane & 15;
      const int kb = (lane >> 4) * 8;
      bf16x8 af[2], bfr[4];
      #pragma unroll
      for (int i = 0; i < 2; ++i)
        af[i] = *(const bf16x8*)(As + (wm + i * 16 + r) * 32 + kb);
      #pragma unroll
      for (int j = 0; j < 4; ++j)
        bfr[j] = *(const bf16x8*)(Bs + (j * 16 + r) * 32 + kb);
      #pragma unroll
      for (int i = 0; i < 2; ++i)
        #pragma unroll
        for (int j = 0; j < 4; ++j)
          acc[i][j] = __builtin_amdgcn_mfma_f32_16x16x32_bf16(af[i], bfr[j], acc[i][j], 0, 0, 0);
    }
    const int cl = lane & 15;
    const int rl = (lane >> 4) * 4;
    #pragma unroll
    for (int i = 0; i < 2; ++i) {
      #pragma unroll
      for (int rr = 0; rr < 4; ++rr) {
        const int row = m0 + wm + i * 16 + rl + rr;   // = b*8+s
        const int bb = row >> 3, ss = row & 7;
        const float sp = p3[(size_t)(bb * 64 + h * 8 + ss) * 4 + 3];
        #pragma unroll
        for (int j = 0; j < 4; ++j) {
          const int col = h * 64 + j * 16 + cl;
          att[(size_t)row * 512 + col] = acc[i][j][rr] + sp * bvv[col];
        }
      }
    }
  } else {
    const int j = bid - 16;
    const int b = j >> 3, ch = j & 7;
    const int e8 = tid & 63, tp = tid >> 6;
    float w[8], acc[8];
    #pragma unroll
    for (int k = 0; k < 8; ++k) { w[k] = w_rep[e8 * 8 + k]; acc[k] = 0.f; }
    const int t0 = ch * 128 + tp * 32;
    for (int tt = 0; tt < 32; ++tt) {
      uint4 v = *(const uint4*)(x + ((size_t)(b * 1024 + t0 + tt) << 9) + e8 * 8);
      const u16* pv = (const u16*)&v;
      #pragma unroll
      for (int k = 0; k < 8; ++k) acc[k] += fmaxf(w[k] * b2f(pv[k]), 0.f);
    }
    #pragma unroll
    for (int k = 0; k < 8; ++k) ps[tp][e8 * 8 + k] = acc[k];
    __syncthreads();
    #pragma unroll
    for (int r = 0; r < 2; ++r) {
      int e = r * 256 + tid;
      gpart[(size_t)(b * 8 + ch) * 512 + e] = ps[0][e] + ps[1][e] + ps[2][e] + ps[3][e];
    }
  }
}

// ---------------- LN1: m = LN(memory+att) -> m_f32, m_bf16 ----------------
__global__ __launch_bounds__(256) void k_ln1(
    const float* __restrict__ memory, const float* __restrict__ att,
    const float* __restrict__ g1, const float* __restrict__ be1,
    float* __restrict__ m_f32, u16* __restrict__ m_bf)
{
  const int b = blockIdx.x, s = blockIdx.y;
  const int tid = threadIdx.x;
  __shared__ float r1[256], r2[256];
  const size_t base = (size_t)(b * 8 + s) * 512;
  float v0 = memory[base + tid] + att[base + tid];
  float v1 = memory[base + 256 + tid] + att[base + 256 + tid];
  r1[tid] = v0 + v1; r2[tid] = v0 * v0 + v1 * v1;
  __syncthreads();
  for (int off = 128; off > 0; off >>= 1) {
    if (tid < off) { r1[tid] += r1[tid + off]; r2[tid] += r2[tid + off]; }
    __syncthreads();
  }
  float mu = r1[0] * (1.f / 512.f);
  float var = r2[0] * (1.f / 512.f) - mu * mu;
  float rs = rsqrtf(var + 1e-5f);
  float m0v = (v0 - mu) * rs * g1[tid] + be1[tid];
  float m1v = (v1 - mu) * rs * g1[tid + 256] + be1[tid + 256];
  m_f32[base + tid] = m0v;
  m_f32[base + 256 + tid] = m1v;
  m_bf[base + tid] = f2b(m0v);
  m_bf[base + 256 + tid] = f2b(m1v);
}

// ---------------- merged: blocks 0-7 = MLP MFMA GEMM, 8-263 = gm partials, 264-295 = gi-gate partials ----------------
__global__ __launch_bounds__(256) void k_mlpgigm(
    const u16* __restrict__ A, const u16* __restrict__ Bt,
    const float* __restrict__ b_mlp, const float* __restrict__ m_f32,
    float* __restrict__ hbuf,
    const float* __restrict__ tm, const float* __restrict__ W_mg, float* __restrict__ gmp,
    const float* __restrict__ gpart, const float* __restrict__ W_ig,
    const float* __restrict__ b_ig, float* __restrict__ gip)
{
  __shared__ __align__(16) char smem[73728];
  const int bid = blockIdx.x;
  const int tid = threadIdx.x;
  if (bid < 8) {
    u16* As = (u16*)smem;               // 16 KB
    u16* Bs = (u16*)(smem + 16384);     // 16 KB
    const int m0 = (bid >> 2) * 128;
    const int n0 = (bid & 3) * 128;
    const int lane = tid & 63;
    const int wid = tid >> 6;
    const int wm = (wid >> 1) * 64;
    const int wn = (wid & 1) * 64;

    f32x4 acc[4][4];
    #pragma unroll
    for (int i = 0; i < 4; ++i)
      #pragma unroll
      for (int j = 0; j < 4; ++j) acc[i][j] = (f32x4){0.f, 0.f, 0.f, 0.f};

    for (int kt = 0; kt < 8; ++kt) {
      const int k0 = kt << 6;
      __syncthreads();
      #pragma unroll
      for (int c = 0; c < 4; ++c) {
        const int q = c * 256 + tid;
        const int row = q >> 3;
        const int c8 = q & 7;
        const int lc = c8 ^ (row & 7);
        gload_lds16(A  + (size_t)(m0 + row) * 512 + k0 + lc * 8, As + q * 8);
        gload_lds16(Bt + (size_t)(n0 + row) * 512 + k0 + lc * 8, Bs + q * 8);
      }
      __syncthreads();
      const int r = lane & 15;
      const int hi = lane >> 4;
      bf16x8 af[4][2], bfr[4][2];
      #pragma unroll
      for (int i = 0; i < 4; ++i) {
        const int ra = wm + i * 16 + r;
        const int rb = wn + i * 16 + r;
        #pragma unroll
        for (int kk = 0; kk < 2; ++kk) {
          af[i][kk]  = *(const bf16x8*)(As + ra * 64 + (((kk * 4 + hi)) ^ (ra & 7)) * 8);
          bfr[i][kk] = *(const bf16x8*)(Bs + rb * 64 + (((kk * 4 + hi)) ^ (rb & 7)) * 8);
        }
      }
      #pragma unroll
      for (int kk = 0; kk < 2; ++kk)
        #pragma unroll
        for (int i = 0; i < 4; ++i)
          #pragma unroll
          for (int j = 0; j < 4; ++j)
            acc[i][j] = __builtin_amdgcn_mfma_f32_16x16x32_bf16(af[i][kk], bfr[j][kk], acc[i][j], 0, 0, 0);
    }
    const int cl = lane & 15;
    const int rl = (lane >> 4) * 4;
    #pragma unroll
    for (int j = 0; j < 4; ++j) {
      const int col = n0 + wn + j * 16 + cl;
      const float bsv = b_mlp[col];
      #pragma unroll
      for (int i = 0; i < 4; ++i) {
        #pragma unroll
        for (int rr = 0; rr < 4; ++rr) {
          const int row = m0 + wm + i * 16 + rl + rr;
          hbuf[(size_t)row * 512 + col] = m_f32[(size_t)row * 512 + col] + fmaxf(acc[i][j][rr] + bsv, 0.f);
        }
      }
    }
  } else if (bid < 264) {
    float* wtile = (float*)smem;            // 64 KB
    float* vals  = (float*)(smem + 65536);  // 8 KB
    const int g = bid - 8;
    const int s = g >> 5, nc = (g >> 3) & 3, kc = g & 7;
    const int k0 = kc * 64;
    const float* wsrc = W_mg + (size_t)s * 524288 + (size_t)k0 * 1024 + nc * 256;
    #pragma unroll
    for (int i = 0; i < 16; ++i) {
      const int q = i * 256 + tid;          // 4096 chunks of 16B; each wave = one row
      const int row = q >> 6, c16 = q & 63;
      gload_lds16(wsrc + (size_t)row * 1024 + c16 * 4, wtile + q * 4);
    }
    {
      int i = tid * 2;
      int b = i >> 4, k4 = i & 15;
      *(float4*)&vals[b * 64 + k4 * 4] = *(const float4*)&tm[(size_t)(b * 8 + s) * 512 + k0 + k4 * 4];
      i++;
      b = i >> 4; k4 = i & 15;
      *(float4*)&vals[b * 64 + k4 * 4] = *(const float4*)&tm[(size_t)(b * 8 + s) * 512 + k0 + k4 * 4];
    }
    __syncthreads();
    const int col = nc * 256 + tid;
    float acc[32];
    #pragma unroll
    for (int b = 0; b < 32; ++b) acc[b] = 0.f;
    for (int kk = 0; kk < 64; ++kk) {
      float w = wtile[kk * 256 + tid];
      #pragma unroll
      for (int b = 0; b < 32; ++b) acc[b] += vals[b * 64 + kk] * w;
    }
    #pragma unroll
    for (int b = 0; b < 32; ++b)
      gmp[(size_t)((kc * 32 + b) * 8 + s) * 1024 + col] = acc[b];
  } else {
    float* wtile = (float*)smem;
    float* vals  = (float*)(smem + 65536);
    const int j = bid - 264;             // 0..31
    const int nc = j >> 3, kc = j & 7;
    const int k0 = kc * 64;
    const float* wsrc = W_ig + (size_t)k0 * 1024 + nc * 256;
    #pragma unroll
    for (int i = 0; i < 16; ++i) {
      const int q = i * 256 + tid;
      const int row = q >> 6, c16 = q & 63;
      gload_lds16(wsrc + (size_t)row * 1024 + c16 * 4, wtile + q * 4);
    }
    #pragma unroll
    for (int i = 0; i < 8; ++i) {
      const int idx = i * 256 + tid;        // 2048 = 32 b x 64 k
      const int b = idx >> 6, k = idx & 63;
      float a = 0.f;
      #pragma unroll
      for (int ch = 0; ch < 8; ++ch)
        a += gpart[(size_t)(b * 8 + ch) * 512 + k0 + k];
      vals[b * 64 + k] = a * (1.f / 1024.f);
    }
    __syncthreads();
    const int col = nc * 256 + tid;
    float acc[32];
    #pragma unroll
    for (int b = 0; b < 32; ++b) acc[b] = 0.f;
    for (int kk = 0; kk < 64; ++kk) {
      float w = wtile[kk * 256 + tid];
      #pragma unroll
      for (int b = 0; b < 32; ++b) acc[b] += vals[b * 64 + kk] * w;
    }
    const float badd = (kc == 0) ? b_ig[col] : 0.f;
    #pragma unroll
    for (int b = 0; b < 32; ++b)
      gip[(size_t)(kc * 32 + b) * 1024 + col] = acc[b] + badd;
  }
}

// ---------------- kv partials with fused LN2+gating: nmem slice computed in-block ----------------
// Replaces k_ln2gate + k_kv_part: each (b,nc,kc) block computes the gated-memory slice
// nm[8][128] (e in [kc*128, kc*128+128)) from hbuf row-stats + gm/gi partials, then the
// kv partial matmul. 5x nc-redundancy on the gate math (~0.5MB) is cheap vs a launch+round-trip.
__global__ __launch_bounds__(256) void k_kvgate(
    const float* __restrict__ hbuf, const float* __restrict__ g2, const float* __restrict__ be2,
    const float* __restrict__ gip, const float* __restrict__ gmp,
    const float* __restrict__ b_mg, const float* __restrict__ memory,
    const float* __restrict__ fbias, const float* __restrict__ ibias,
    const float* __restrict__ Wk, const float* __restrict__ Wv,
    float* __restrict__ kvp)
{
  const int b = blockIdx.x, nc = blockIdx.y, kc = blockIdx.z;
  const int tid = threadIdx.x;
  const int k0 = kc * 128;
  __shared__ float hb[8][512];
  __shared__ float red[2][8][32];
  __shared__ float mus[8], rss[8];
  __shared__ float nm[8][128];
  #pragma unroll
  for (int i = 0; i < 4; ++i) {
    int idx = i * 256 + tid;
    int s = idx >> 7, c4 = idx & 127;
    *(float4*)&hb[s][c4 * 4] = *(const float4*)&hbuf[(size_t)(b * 8 + s) * 512 + c4 * 4];
  }
  __syncthreads();
  {
    int s = tid >> 5, l = tid & 31;
    float sm = 0.f, sq = 0.f;
    #pragma unroll
    for (int j = 0; j < 16; ++j) {
      float v = hb[s][l * 16 + j];
      sm += v; sq += v * v;
    }
    red[0][s][l] = sm; red[1][s][l] = sq;
  }
  __syncthreads();
  if (tid < 8) {
    float sm = 0.f, sq = 0.f;
    #pragma unroll
    for (int l = 0; l < 32; ++l) { sm += red[0][tid][l]; sq += red[1][tid][l]; }
    float mu = sm * (1.f / 512.f);
    float var = sq * (1.f / 512.f) - mu * mu;
    mus[tid] = mu;
    rss[tid] = rsqrtf(var + 1e-5f);
  }
  __syncthreads();
  const float fb = fbias[0], ib = ibias[0];
  #pragma unroll
  for (int i = 0; i < 4; ++i) {
    int idx = i * 256 + tid;
    int s = idx >> 7, ee = idx & 127;
    int e = k0 + ee;
    float ln = (hb[s][e] - mus[s]) * rss[s] * g2[e] + be2[e];
    float gin = b_mg[s * 1024 + e], gfn = b_mg[s * 1024 + 512 + e];
    #pragma unroll
    for (int kc2 = 0; kc2 < 8; ++kc2) {
      size_t gp = (size_t)((kc2 * 32 + b) * 8 + s) * 1024;
      gin += gmp[gp + e];
      gfn += gmp[gp + 512 + e];
    }
    float giv_i = 0.f, giv_f = 0.f;
    #pragma unroll
    for (int kc2 = 0; kc2 < 8; ++kc2) {
      size_t gp = (size_t)(kc2 * 32 + b) * 1024;
      giv_i += gip[gp + e];
      giv_f += gip[gp + 512 + e];
    }
    float ing = 1.f / (1.f + __expf(-(giv_i + gin + ib)));
    float fg  = 1.f / (1.f + __expf(-(giv_f + gfn + fb)));
    nm[s][ee] = ing * tanhf(ln) + fg * memory[(size_t)(b * 8 + s) * 512 + e];
  }
  __syncthreads();
  const int col = tid & 127, rg = tid >> 7;
  const int cg = nc * 128 + col;
  const float* wp; int stride;
  if (nc == 0) { wp = Wk + (size_t)k0 * 128 + cg; stride = 128; }
  else         { wp = Wv + (size_t)k0 * 512 + (cg - 128); stride = 512; }
  const int b0 = rg * 4;
  float a0 = 0.f, a1 = 0.f, a2 = 0.f, a3 = 0.f;
  #pragma unroll 4
  for (int kk = 0; kk < 128; ++kk) {
    float w = wp[(size_t)kk * stride];
    a0 += nm[b0][kk] * w;
    a1 += nm[b0 + 1][kk] * w;
    a2 += nm[b0 + 2][kk] * w;
    a3 += nm[b0 + 3][kk] * w;
  }
  kvp[(size_t)((kc * 32 + b) * 8 + b0    ) * 640 + cg] = a0;
  kvp[(size_t)((kc * 32 + b) * 8 + b0 + 1) * 640 + cg] = a1;
  kvp[(size_t)((kc * 32 + b) * 8 + b0 + 2) * 640 + cg] = a2;
  kvp[(size_t)((kc * 32 + b) * 8 + b0 + 3) * 640 + cg] = a3;
}

// ---------------- final broadcast attention -> out (T,B,E); 16 tokens/block ----------------
__global__ __launch_bounds__(256) void k_out_attn(
    const u16* __restrict__ kq, const float* __restrict__ kvp,
    const float* __restrict__ bk, const float* __restrict__ bv,
    float* __restrict__ out)
{
  int b = blockIdx.x, tc = blockIdx.y;
  int tid = threadIdx.x;
  __shared__ float km[1024];
  __shared__ float vm[4096];
  __shared__ float pr[1024];
  for (int i = tid; i < 1024; i += 256) {
    int s = i >> 7, j = i & 127;
    float a = bk[j];
    #pragma unroll
    for (int kc = 0; kc < 4; ++kc)
      a += kvp[(size_t)((kc * 32 + b) * 8 + s) * 640 + j];
    km[i] = a;
  }
  for (int i = tid; i < 4096; i += 256) {
    int s = i >> 9, c = i & 511;
    float a = bv[c];
    #pragma unroll
    for (int kc = 0; kc < 4; ++kc)
      a += kvp[(size_t)((kc * 32 + b) * 8 + s) * 640 + 128 + c];
    vm[i] = a;
  }
  __syncthreads();
  if (tid < 128) {
    int tt = tid >> 3, hh = tid & 7;
    int t = tc * 16 + tt;
    const u16* qrow = kq + ((size_t)(b * 1024 + t)) * 256 + 128 + hh * 16;
    float q[16];
    #pragma unroll
    for (int d = 0; d < 16; ++d) q[d] = b2f(qrow[d]);
    float s8[8]; float mx = -1e38f;
    #pragma unroll
    for (int s = 0; s < 8; ++s) {
      float a = 0.f;
      #pragma unroll
      for (int d = 0; d < 16; ++d) a += q[d] * km[s * 128 + hh * 16 + d];
      s8[s] = a; mx = fmaxf(mx, a);
    }
    float se = 0.f;
    #pragma unroll
    for (int s = 0; s < 8; ++s) { s8[s] = __expf(s8[s] - mx); se += s8[s]; }
    float inv = 1.f / se;
    #pragma unroll
    for (int s = 0; s < 8; ++s) pr[(tt * 8 + hh) * 8 + s] = s8[s] * inv;
  }
  __syncthreads();
  #pragma unroll
  for (int oi = 0; oi < 8; ++oi) {
    int o = oi * 256 + tid;
    int tt = o >> 7, c4 = o & 127;
    int c = c4 * 4, hh = c >> 6;
    const float* prp = &pr[(tt * 8 + hh) * 8];
    float4 r = {0.f, 0.f, 0.f, 0.f};
    #pragma unroll
    for (int s = 0; s < 8; ++s) {
      float p = prp[s];
      float4 v = *(const float4*)&vm[s * 512 + c];
      r.x += p * v.x; r.y += p * v.y; r.z += p * v.z; r.w += p * v.w;
    }
    int t = tc * 16 + tt;
    *(float4*)&out[((size_t)t * 32 + b) * 512 + c] = r;
  }
}

extern "C" void kernel_launch(void* const* d_in, const int* in_sizes, int n_in,
                              void* d_out, int out_size, void* d_ws, size_t ws_size,
                              hipStream_t stream) {
  (void)in_sizes; (void)n_in; (void)out_size; (void)ws_size;
  const float* key   = (const float*)d_in[1];
  const float* memory= (const float*)d_in[2];
  const float* W_in  = (const float*)d_in[3];
  const float* b_in  = (const float*)d_in[4];
  const float* Wq    = (const float*)d_in[5];
  const float* bq    = (const float*)d_in[6];
  const float* Wk    = (const float*)d_in[7];
  const float* bk    = (const float*)d_in[8];
  const float* Wv    = (const float*)d_in[9];
  const float* bv    = (const float*)d_in[10];
  const float* W_mlp = (const float*)d_in[11];
  const float* b_mlp = (const float*)d_in[12];
  const float* g1    = (const float*)d_in[13];
  const float* be1   = (const float*)d_in[14];
  const float* g2    = (const float*)d_in[15];
  const float* be2   = (const float*)d_in[16];
  const float* w_rep = (const float*)d_in[17];
  const float* W_ig  = (const float*)d_in[18];
  const float* b_ig  = (const float*)d_in[19];
  const float* W_mg  = (const float*)d_in[20];
  const float* b_mg  = (const float*)d_in[21];
  const float* fbias = (const float*)d_in[22];
  const float* ibias = (const float*)d_in[23];
  float* out = (float*)d_out;

  char* p = (char*)d_ws;
  auto alloc = [&](size_t bytes) { char* r = p; p += (bytes + 255) & ~(size_t)255; return r; };
  u16* x       = (u16*)alloc(33554432);    // x bf16 (B*T, 512)
  u16* keyB    = (u16*)alloc(33554432);    // key bf16 (B*T, 512)
  u16* kq      = (u16*)alloc(16777216);    // [k | q] bf16 (B*T, 256)
  u16* WxT     = (u16*)alloc(786432);      // 768 x 512 bf16: [W_in^T ; Wc^T]
  u16* WvT     = (u16*)alloc(524288);
  u16* WkqTr   = (u16*)alloc(262144);
  u16* WinB    = (u16*)alloc(524288);
  u16* WmlpT   = (u16*)alloc(524288);      // W_mlp^T bf16
  float* bfull = (float*)alloc(3072);
  float* gpart = (float*)alloc(524288);    // (B, 8, 512)
  float* gip   = (float*)alloc(1048576);   // (8, B, 1024) partials
  float* gmp   = (float*)alloc(8388608);   // (8, B, S, 1024) partials
  float* att   = (float*)alloc(524288);
  float* m_f32 = (float*)alloc(524288);    // LN1 output f32
  u16*   m_bf  = (u16*)alloc(262144);      // LN1 output bf16
  float* hbuf  = (float*)alloc(524288);    // m + relu(mlp)
  float* kvp   = (float*)alloc(2621440);   // (4, B*8, 640)
  float* tm    = (float*)alloc(524288);
  float* qmw   = (float*)alloc(131072);
  float* p3    = (float*)alloc(32768);
  u16* XW      = (u16*)alloc(2097152);     // (H, 256, 512) bf16

  k_prep<<<13571, 256, 0, stream>>>(W_in, WxT, Wv, WvT, memory, tm, b_in, bfull,
                                    Wk, Wq, WkqTr, WinB, W_mlp, WmlpT, key, keyB,
                                    bk, bq, qmw);
  gemm_wc<<<dim3(2, 4), 256, 0, stream>>>(WkqTr, WinB, WxT);
  gemm_xkq<<<1536, 256, 0, stream>>>(keyB, WxT, bfull, x, kq);
  k_scores_topk<<<dim3(32, 8, 8), 256, 0, stream>>>(qmw, kq, x, p3, XW);
  k_attgi<<<272, 256, 0, stream>>>(XW, WvT, p3, bv, att, x, w_rep, gpart);
  k_ln1<<<dim3(32, 8), 256, 0, stream>>>(memory, att, g1, be1, m_f32, m_bf);
  k_mlpgigm<<<296, 256, 0, stream>>>(m_bf, WmlpT, b_mlp, m_f32, hbuf,
                                     tm, W_mg, gmp, gpart, W_ig, b_ig, gip);
  k_kvgate<<<dim3(32, 5, 4), 256, 0, stream>>>(hbuf, g2, be2, gip, gmp, b_mg, memory,
                                               fbias, ibias, Wk, Wv, kvp);
  k_out_attn<<<dim3(32, 64), 256, 0, stream>>>(kq, kvp, bk, bv, out);
}

// Round 17
// 168.760 us; speedup vs baseline: 1.0510x; 1.0510x over previous
//
#include <hip/hip_runtime.h>
#include <stdint.h>

typedef unsigned short u16;
typedef __bf16 bf16x8 __attribute__((ext_vector_type(8)));
typedef float f32x4 __attribute__((ext_vector_type(4)));

// Problem constants: T=1024, B=32, E=512, HEADS=8, KEYD=16, HEAD=64, MEM_SLOTS=8, TOPK=3

__device__ __forceinline__ u16 f2b(float f) {
  union { __bf16 h; u16 u; } v; v.h = (__bf16)f; return v.u;
}
__device__ __forceinline__ float b2f(u16 h) {
  union { uint32_t u; float f; } v; v.u = ((uint32_t)h) << 16; return v.f;
}
__device__ __forceinline__ void gload_lds16(const void* g, void* l) {
  __builtin_amdgcn_global_load_lds(
      (const __attribute__((address_space(1))) unsigned int*)g,
      (__attribute__((address_space(3))) unsigned int*)l, 16, 0, 0);
}

// ---------------- fused prep: all weight converts + tanh(mem) + bfull[0:512] + keyB ----------------
__global__ void k_prep(const float* __restrict__ W_in, u16* __restrict__ WxT,
                       const float* __restrict__ Wv, u16* __restrict__ WvT,
                       const float* __restrict__ mem, float* __restrict__ tm,
                       const float* __restrict__ b_in, float* __restrict__ bfull,
                       const float* __restrict__ Wk, const float* __restrict__ Wq,
                       u16* __restrict__ WkqTr, u16* __restrict__ WinB,
                       const float* __restrict__ W_mlp, u16* __restrict__ WmlpT,
                       const float* __restrict__ key, u16* __restrict__ keyB) {
  int idx = blockIdx.x * 256 + threadIdx.x;
  if (idx < 262144) {
    int k = idx >> 9, n = idx & 511;
    WxT[n * 512 + k] = f2b(W_in[idx]);
  } else if (idx < 524288) {
    int j = idx - 262144;
    int k = j >> 9, n = j & 511;
    WvT[n * 512 + k] = f2b(Wv[j]);
  } else if (idx < 655360) {
    int j = idx - 524288;
    tm[j] = tanhf(mem[j]);
  } else if (idx < 655872) {
    int j = idx - 655360;
    bfull[j] = b_in[j];
  } else if (idx < 786944) {
    int i = idx - 655872;                 // WkqTr[j][n] = Wkq[n][j]
    int j = i >> 9, n = i & 511;
    WkqTr[i] = f2b(j < 128 ? Wk[n * 128 + j] : Wq[n * 128 + j - 128]);
  } else if (idx < 1049088) {
    int i = idx - 786944;                 // WinB = W_in row-major bf16
    WinB[i] = f2b(W_in[i]);
  } else if (idx < 1311232) {
    int i = idx - 1049088;                // WmlpT[n][k] = W_mlp[k][n]
    int k = i >> 9, n = i & 511;
    WmlpT[n * 512 + k] = f2b(W_mlp[i]);
  } else {
    int i = idx - 1311232;                // keyB: (T,B,E) f32 -> (B*T,E) bf16, 8 elems
    int r = i >> 6, e8 = i & 63;
    int b = r >> 10, t = r & 1023;
    const float* src = key + ((size_t)(t * 32 + b) << 9) + e8 * 8;
    float4 lo = *(const float4*)src;
    float4 hi = *(const float4*)(src + 4);
    bf16x8 o;
    o[0] = (__bf16)lo.x; o[1] = (__bf16)lo.y; o[2] = (__bf16)lo.z; o[3] = (__bf16)lo.w;
    o[4] = (__bf16)hi.x; o[5] = (__bf16)hi.y; o[6] = (__bf16)hi.z; o[7] = (__bf16)hi.w;
    *(bf16x8*)(keyB + ((size_t)r << 9) + e8 * 8) = o;
  }
}

// ---------------- stage-2: blocks 0-7 Wc^T MFMA; 8-39 qm (LDS-staged, r16 fix); 40 bias ----------------
// r16 lesson: old qm branch was a 256-deep serial strided-load chain (~40us, hidden since r5).
// Fix = r13 recipe: stage the contiguous 64KB Wq k-tile via global_load_lds, compute from LDS.
__global__ __launch_bounds__(256) void k_wprep2(
    const u16* __restrict__ A, const u16* __restrict__ Bt, u16* __restrict__ WxT,
    const float* __restrict__ Wq, const float* __restrict__ memory,
    const float* __restrict__ bq, float* __restrict__ qm,
    const float* __restrict__ b_in, const float* __restrict__ bk,
    float* __restrict__ bfull)
{
  __shared__ __align__(16) char smem[69632];   // 68 KB union
  const int bid = blockIdx.x;
  const int tid = threadIdx.x;
  if (bid < 8) {
    u16* As = (u16*)smem;                      // 8 KB
    u16* Bs = (u16*)(smem + 8192);             // 8 KB
    const int m0 = (bid & 1) * 128;
    const int n0 = (bid >> 1) * 128;
    const int lane = tid & 63;
    const int wid = tid >> 6;
    const int wm = (wid >> 1) * 64;
    const int wn = (wid & 1) * 64;
    f32x4 acc[4][4];
    #pragma unroll
    for (int i = 0; i < 4; ++i)
      #pragma unroll
      for (int j = 0; j < 4; ++j) acc[i][j] = (f32x4){0.f, 0.f, 0.f, 0.f};
    for (int kt = 0; kt < 16; ++kt) {
      const int k0 = kt << 5;
      __syncthreads();
      #pragma unroll
      for (int c = 0; c < 2; ++c) {
        int o = c * 2048 + tid * 8;
        int row = o >> 5, ck = o & 31;
        gload_lds16(A + (size_t)(m0 + row) * 512 + k0 + ck, As + o);
        gload_lds16(Bt + (size_t)(n0 + row) * 512 + k0 + ck, Bs + o);
      }
      __syncthreads();
      const int r = lane & 15;
      const int kb = (lane >> 4) * 8;
      bf16x8 af[4], bfr[4];
      #pragma unroll
      for (int i = 0; i < 4; ++i) {
        af[i]  = *(const bf16x8*)(As + (wm + i * 16 + r) * 32 + kb);
        bfr[i] = *(const bf16x8*)(Bs + (wn + i * 16 + r) * 32 + kb);
      }
      #pragma unroll
      for (int i = 0; i < 4; ++i)
        #pragma unroll
        for (int j = 0; j < 4; ++j)
          acc[i][j] = __builtin_amdgcn_mfma_f32_16x16x32_bf16(af[i], bfr[j], acc[i][j], 0, 0, 0);
    }
    const int cl = lane & 15;
    const int rl = (lane >> 4) * 4;
    #pragma unroll
    for (int j = 0; j < 4; ++j) {
      const int col = n0 + wn + j * 16 + cl;
      #pragma unroll
      for (int i = 0; i < 4; ++i) {
        #pragma unroll
        for (int rr = 0; rr < 4; ++rr) {
          const int row = m0 + wm + i * 16 + rl + rr;
          WxT[(size_t)(512 + row) * 512 + col] = f2b(acc[i][j][rr]);
        }
      }
    }
  } else if (bid < 40) {
    // qm[b,s,:] = memory[b,s,:] @ Wq + bq, b = bid-8; f32, LDS-staged Wq tiles
    float* wq = (float*)smem;                  // 64 KB: 128 k-rows x 128 cols
    float* mr = (float*)(smem + 65536);        // 4 KB: 8 s x 128
    const int b = bid - 8;
    const int col = tid & 127, sg = tid >> 7;
    float a0 = 0.f, a1 = 0.f, a2 = 0.f, a3 = 0.f;
    for (int kc = 0; kc < 4; ++kc) {
      #pragma unroll
      for (int i = 0; i < 16; ++i) {
        int q = i * 256 + tid;                 // 4096 chunks of 16B, contiguous 64KB
        gload_lds16(Wq + kc * 16384 + q * 4, wq + q * 4);
      }
      {
        int s = tid >> 5, o = (tid & 31) * 4;  // 256 chunks of 16B
        gload_lds16(memory + (size_t)(b * 8 + s) * 512 + kc * 128 + o, mr + s * 128 + o);
      }
      __syncthreads();
      const float* m0p = mr + (sg * 4 + 0) * 128;
      const float* m1p = mr + (sg * 4 + 1) * 128;
      const float* m2p = mr + (sg * 4 + 2) * 128;
      const float* m3p = mr + (sg * 4 + 3) * 128;
      #pragma unroll 4
      for (int kk = 0; kk < 128; ++kk) {
        float w = wq[kk * 128 + col];
        a0 += m0p[kk] * w;
        a1 += m1p[kk] * w;
        a2 += m2p[kk] * w;
        a3 += m3p[kk] * w;
      }
      __syncthreads();
    }
    const float bqv = bq[col];
    qm[(size_t)(b * 8 + sg * 4 + 0) * 128 + col] = a0 + bqv;
    qm[(size_t)(b * 8 + sg * 4 + 1) * 128 + col] = a1 + bqv;
    qm[(size_t)(b * 8 + sg * 4 + 2) * 128 + col] = a2 + bqv;
    qm[(size_t)(b * 8 + sg * 4 + 3) * 128 + col] = a3 + bqv;
  } else {
    // bfull[512+j] = b_in @ Wkq[:,j] + bkq[j], via contiguous bf16 WkqTr rows
    float* sh = (float*)smem;
    sh[tid] = b_in[tid];
    sh[256 + tid] = b_in[256 + tid];
    __syncthreads();
    const u16* wr = A + (size_t)tid * 512;     // A = WkqTr
    float a = 0.f;
    for (int c = 0; c < 64; ++c) {
      uint4 v = *(const uint4*)(wr + c * 8);
      const u16* pv = (const u16*)&v;
      #pragma unroll
      for (int k = 0; k < 8; ++k) a += b2f(pv[k]) * sh[c * 8 + k];
    }
    bfull[512 + tid] = a + ((tid < 128) ? bk[tid] : bq[tid - 128]);
  }
}

// ---------------- fused GEMM: [x | kq] = keyB @ WxT^T + bfull  (M=32768, N=768, K=512) ----------------
__global__ __launch_bounds__(256) void gemm_xkq(
    const u16* __restrict__ keyB, const u16* __restrict__ Bt,
    const float* __restrict__ bias, u16* __restrict__ x, u16* __restrict__ kq)
{
  __shared__ u16 smem[16384];               // As[8192] | Bs[8192]; aliased as Cs[128*128]
  u16* As = smem;
  u16* Bs = smem + 8192;
  const int tid = threadIdx.x;
  const int bid = blockIdx.x;                     // 1536 blocks
  const int wgid = (bid & 7) * 192 + (bid >> 3);  // XCD swizzle (1536 % 8 == 0, bijective)
  const int m0 = (wgid / 6) * 128;
  const int n0 = (wgid % 6) * 128;
  const int lane = tid & 63;
  const int wid = tid >> 6;
  const int wm = (wid >> 1) * 64;
  const int wn = (wid & 1) * 64;

  f32x4 acc[4][4];
  #pragma unroll
  for (int i = 0; i < 4; ++i)
    #pragma unroll
    for (int j = 0; j < 4; ++j) acc[i][j] = (f32x4){0.f, 0.f, 0.f, 0.f};

  for (int kt = 0; kt < 8; ++kt) {
    const int k0 = kt << 6;
    __syncthreads();
    #pragma unroll
    for (int c = 0; c < 4; ++c) {
      const int q = c * 256 + tid;     // 16B chunk id, 0..1023
      const int row = q >> 3;          // 0..127
      const int c8 = q & 7;            // chunk slot within row
      const int lc = c8 ^ (row & 7);   // pre-swizzled global chunk
      gload_lds16(keyB + (size_t)(m0 + row) * 512 + k0 + lc * 8, As + q * 8);
      gload_lds16(Bt   + (size_t)(n0 + row) * 512 + k0 + lc * 8, Bs + q * 8);
    }
    __syncthreads();
    const int r = lane & 15;
    const int hi = lane >> 4;
    bf16x8 af[4][2], bfr[4][2];
    #pragma unroll
    for (int i = 0; i < 4; ++i) {
      const int ra = wm + i * 16 + r;
      const int rb = wn + i * 16 + r;
      #pragma unroll
      for (int kk = 0; kk < 2; ++kk) {
        af[i][kk]  = *(const bf16x8*)(As + ra * 64 + (((kk * 4 + hi)) ^ (ra & 7)) * 8);
        bfr[i][kk] = *(const bf16x8*)(Bs + rb * 64 + (((kk * 4 + hi)) ^ (rb & 7)) * 8);
      }
    }
    #pragma unroll
    for (int kk = 0; kk < 2; ++kk)
      #pragma unroll
      for (int i = 0; i < 4; ++i)
        #pragma unroll
        for (int j = 0; j < 4; ++j)
          acc[i][j] = __builtin_amdgcn_mfma_f32_16x16x32_bf16(af[i][kk], bfr[j][kk], acc[i][j], 0, 0, 0);
  }
  // epilogue: stage C tile in LDS, then coalesced uint4 stores (full 64B lines)
  __syncthreads();
  u16* Cs = smem;
  const int cl = lane & 15;
  const int rl = (lane >> 4) * 4;
  #pragma unroll
  for (int j = 0; j < 4; ++j) {
    const int lcol = wn + j * 16 + cl;
    const float bsv = bias[n0 + lcol];
    #pragma unroll
    for (int i = 0; i < 4; ++i)
      #pragma unroll
      for (int rr = 0; rr < 4; ++rr)
        Cs[(wm + i * 16 + rl + rr) * 128 + lcol] = f2b(acc[i][j][rr] + bsv);
  }
  __syncthreads();
  #pragma unroll
  for (int c = 0; c < 8; ++c) {
    const int chunk = c * 256 + tid;        // 2048 chunks of 8 u16
    const int row = chunk >> 4, c8 = chunk & 15;
    uint4 v = *(const uint4*)&Cs[row * 128 + c8 * 8];
    if (n0 < 512)
      *(uint4*)(x + (size_t)(m0 + row) * 512 + n0 + c8 * 8) = v;
    else
      *(uint4*)(kq + (size_t)(m0 + row) * 256 + (n0 - 512) + c8 * 8) = v;
  }
}

// ---------------- scores + top3 + softmax per (b,h,s), fused XW write ----------------
__global__ __launch_bounds__(256) void k_scores_topk(
    const float* __restrict__ qm, const u16* __restrict__ kq,
    const u16* __restrict__ x, float* __restrict__ p3, u16* __restrict__ XW)
{
  const int b = blockIdx.x, h = blockIdx.y, s = blockIdx.z;
  const int tid = threadIdx.x;
  __shared__ float swv[4];
  __shared__ int   swi[4];
  __shared__ float ssv[4];

  float q[16];
  const float* qp = qm + ((size_t)(b * 8 + s) * 128 + h * 16);
  #pragma unroll
  for (int d = 0; d < 16; ++d) q[d] = qp[d];

  float sc[4];
  #pragma unroll
  for (int j = 0; j < 4; ++j) {
    const int t = j * 256 + tid;
    const u16* kr = kq + ((size_t)(b * 1024 + t)) * 256 + h * 16;
    uint4 v0 = *(const uint4*)kr;
    uint4 v1 = *(const uint4*)(kr + 8);
    const u16* p0 = (const u16*)&v0;
    const u16* p1 = (const u16*)&v1;
    float a = 0.f;
    #pragma unroll
    for (int d = 0; d < 8; ++d) a += q[d] * b2f(p0[d]);
    #pragma unroll
    for (int d = 0; d < 8; ++d) a += q[8 + d] * b2f(p1[d]);
    sc[j] = a;
  }

  int   seli[3];
  float selv[3];
  float ssum = 0.f;
  #pragma unroll
  for (int pass = 0; pass < 3; ++pass) {
    float bv_ = -1e30f; int bi_ = 1 << 30;
    #pragma unroll
    for (int j = 0; j < 4; ++j) {
      const int t = j * 256 + tid;
      bool skip = false;
      for (int k = 0; k < pass; ++k) skip |= (t == seli[k]);
      float v = skip ? -1e30f : sc[j];
      if (v > bv_ || (v == bv_ && t < bi_)) { bv_ = v; bi_ = t; }
    }
    #pragma unroll
    for (int o = 32; o > 0; o >>= 1) {
      float ov = __shfl_xor(bv_, o);
      int   oi = __shfl_xor(bi_, o);
      if (ov > bv_ || (ov == bv_ && oi < bi_)) { bv_ = ov; bi_ = oi; }
    }
    __syncthreads();
    if ((tid & 63) == 0) { swv[tid >> 6] = bv_; swi[tid >> 6] = bi_; }
    __syncthreads();
    float wv = swv[0]; int wi = swi[0];
    #pragma unroll
    for (int w = 1; w < 4; ++w) {
      float ov = swv[w]; int oi = swi[w];
      if (ov > wv || (ov == wv && oi < wi)) { wv = ov; wi = oi; }
    }
    selv[pass] = wv; seli[pass] = wi;

    if (pass == 0) {
      float se = 0.f;
      #pragma unroll
      for (int j = 0; j < 4; ++j) se += __expf(sc[j] - wv);
      #pragma unroll
      for (int o = 32; o > 0; o >>= 1) se += __shfl_xor(se, o);
      __syncthreads();
      if ((tid & 63) == 0) ssv[tid >> 6] = se;
      __syncthreads();
      ssum = ssv[0] + ssv[1] + ssv[2] + ssv[3];
    }
  }

  const float m0v = selv[0];
  const float inv = 1.f / ssum;
  const float p0 = __expf(selv[0] - m0v) * inv;
  const float p1 = __expf(selv[1] - m0v) * inv;
  const float p2 = __expf(selv[2] - m0v) * inv;
  if (tid == 0) {
    const size_t base = (size_t)(b * 64 + h * 8 + s);
    p3[base * 4 + 0] = p0;
    p3[base * 4 + 1] = p1;
    p3[base * 4 + 2] = p2;
    p3[base * 4 + 3] = p0 + p1 + p2;
  }
  if (tid < 64) {
    const u16* xb = x + ((size_t)b << 19) + tid * 8;
    uint4 a0 = *(const uint4*)(xb + ((size_t)seli[0] << 9));
    uint4 a1 = *(const uint4*)(xb + ((size_t)seli[1] << 9));
    uint4 a2 = *(const uint4*)(xb + ((size_t)seli[2] << 9));
    const u16* e0 = (const u16*)&a0;
    const u16* e1 = (const u16*)&a1;
    const u16* e2 = (const u16*)&a2;
    u16 ov[8];
    #pragma unroll
    for (int k = 0; k < 8; ++k)
      ov[k] = f2b(p0 * b2f(e0[k]) + p1 * b2f(e1[k]) + p2 * b2f(e2[k]));
    *(uint4*)(XW + (size_t)h * 131072 + (size_t)(b * 8 + s) * 512 + tid * 8) = *(const uint4*)ov;
  }
}

// ---------------- merged: blocks 0-15 = att per-head MFMA GEMM, 16-271 = gi partials ----------------
__global__ __launch_bounds__(256) void k_attgi(
    const u16* __restrict__ XW, const u16* __restrict__ WvT,
    const float* __restrict__ p3, const float* __restrict__ bvv,
    float* __restrict__ att,
    const u16* __restrict__ x, const float* __restrict__ w_rep,
    float* __restrict__ gpart)
{
  __shared__ u16 As[128 * 32];
  __shared__ u16 Bs[64 * 32];
  __shared__ float ps[4][512];
  const int bid = blockIdx.x;
  const int tid = threadIdx.x;
  if (bid < 16) {
    const int h = bid >> 1;
    const int m0 = (bid & 1) * 128;
    const int lane = tid & 63;
    const int wid = tid >> 6;
    const int wm = wid * 32;
    const u16* A = XW + (size_t)h * 131072;
    const u16* Bh = WvT + (size_t)h * 64 * 512;

    f32x4 acc[2][4];
    #pragma unroll
    for (int i = 0; i < 2; ++i)
      #pragma unroll
      for (int j = 0; j < 4; ++j) acc[i][j] = (f32x4){0.f, 0.f, 0.f, 0.f};

    for (int kt = 0; kt < 16; ++kt) {
      const int k0 = kt << 5;
      __syncthreads();
      #pragma unroll
      for (int c = 0; c < 2; ++c) {
        int o = c * 2048 + tid * 8;
        int row = o >> 5, ck = o & 31;
        gload_lds16(A + (size_t)(m0 + row) * 512 + k0 + ck, As + o);
      }
      {
        int row = tid >> 2, ck = (tid & 3) * 8;
        gload_lds16(Bh + (size_t)row * 512 + k0 + ck, Bs + row * 32 + ck);
      }
      __syncthreads();
      const int r = lane & 15;
      const int kb = (lane >> 4) * 8;
      bf16x8 af[2], bfr[4];
      #pragma unroll
      for (int i = 0; i < 2; ++i)
        af[i] = *(const bf16x8*)(As + (wm + i * 16 + r) * 32 + kb);
      #pragma unroll
      for (int j = 0; j < 4; ++j)
        bfr[j] = *(const bf16x8*)(Bs + (j * 16 + r) * 32 + kb);
      #pragma unroll
      for (int i = 0; i < 2; ++i)
        #pragma unroll
        for (int j = 0; j < 4; ++j)
          acc[i][j] = __builtin_amdgcn_mfma_f32_16x16x32_bf16(af[i], bfr[j], acc[i][j], 0, 0, 0);
    }
    const int cl = lane & 15;
    const int rl = (lane >> 4) * 4;
    #pragma unroll
    for (int i = 0; i < 2; ++i) {
      #pragma unroll
      for (int rr = 0; rr < 4; ++rr) {
        const int row = m0 + wm + i * 16 + rl + rr;   // = b*8+s
        const int bb = row >> 3, ss = row & 7;
        const float sp = p3[(size_t)(bb * 64 + h * 8 + ss) * 4 + 3];
        #pragma unroll
        for (int j = 0; j < 4; ++j) {
          const int col = h * 64 + j * 16 + cl;
          att[(size_t)row * 512 + col] = acc[i][j][rr] + sp * bvv[col];
        }
      }
    }
  } else {
    const int j = bid - 16;
    const int b = j >> 3, ch = j & 7;
    const int e8 = tid & 63, tp = tid >> 6;
    float w[8], acc[8];
    #pragma unroll
    for (int k = 0; k < 8; ++k) { w[k] = w_rep[e8 * 8 + k]; acc[k] = 0.f; }
    const int t0 = ch * 128 + tp * 32;
    for (int tt = 0; tt < 32; ++tt) {
      uint4 v = *(const uint4*)(x + ((size_t)(b * 1024 + t0 + tt) << 9) + e8 * 8);
      const u16* pv = (const u16*)&v;
      #pragma unroll
      for (int k = 0; k < 8; ++k) acc[k] += fmaxf(w[k] * b2f(pv[k]), 0.f);
    }
    #pragma unroll
    for (int k = 0; k < 8; ++k) ps[tp][e8 * 8 + k] = acc[k];
    __syncthreads();
    #pragma unroll
    for (int r = 0; r < 2; ++r) {
      int e = r * 256 + tid;
      gpart[(size_t)(b * 8 + ch) * 512 + e] = ps[0][e] + ps[1][e] + ps[2][e] + ps[3][e];
    }
  }
}

// ---------------- LN1: m = LN(memory+att) -> m_f32, m_bf16 ----------------
__global__ __launch_bounds__(256) void k_ln1(
    const float* __restrict__ memory, const float* __restrict__ att,
    const float* __restrict__ g1, const float* __restrict__ be1,
    float* __restrict__ m_f32, u16* __restrict__ m_bf)
{
  const int b = blockIdx.x, s = blockIdx.y;
  const int tid = threadIdx.x;
  __shared__ float r1[256], r2[256];
  const size_t base = (size_t)(b * 8 + s) * 512;
  float v0 = memory[base + tid] + att[base + tid];
  float v1 = memory[base + 256 + tid] + att[base + 256 + tid];
  r1[tid] = v0 + v1; r2[tid] = v0 * v0 + v1 * v1;
  __syncthreads();
  for (int off = 128; off > 0; off >>= 1) {
    if (tid < off) { r1[tid] += r1[tid + off]; r2[tid] += r2[tid + off]; }
    __syncthreads();
  }
  float mu = r1[0] * (1.f / 512.f);
  float var = r2[0] * (1.f / 512.f) - mu * mu;
  float rs = rsqrtf(var + 1e-5f);
  float m0v = (v0 - mu) * rs * g1[tid] + be1[tid];
  float m1v = (v1 - mu) * rs * g1[tid + 256] + be1[tid + 256];
  m_f32[base + tid] = m0v;
  m_f32[base + 256 + tid] = m1v;
  m_bf[base + tid] = f2b(m0v);
  m_bf[base + 256 + tid] = f2b(m1v);
}

// ---------------- merged: blocks 0-7 = MLP MFMA GEMM, 8-263 = gm partials, 264-295 = gi-gate partials ----------------
__global__ __launch_bounds__(256) void k_mlpgigm(
    const u16* __restrict__ A, const u16* __restrict__ Bt,
    const float* __restrict__ b_mlp, const float* __restrict__ m_f32,
    float* __restrict__ hbuf,
    const float* __restrict__ tm, const float* __restrict__ W_mg, float* __restrict__ gmp,
    const float* __restrict__ gpart, const float* __restrict__ W_ig,
    const float* __restrict__ b_ig, float* __restrict__ gip)
{
  __shared__ __align__(16) char smem[73728];
  const int bid = blockIdx.x;
  const int tid = threadIdx.x;
  if (bid < 8) {
    u16* As = (u16*)smem;               // 16 KB
    u16* Bs = (u16*)(smem + 16384);     // 16 KB
    const int m0 = (bid >> 2) * 128;
    const int n0 = (bid & 3) * 128;
    const int lane = tid & 63;
    const int wid = tid >> 6;
    const int wm = (wid >> 1) * 64;
    const int wn = (wid & 1) * 64;

    f32x4 acc[4][4];
    #pragma unroll
    for (int i = 0; i < 4; ++i)
      #pragma unroll
      for (int j = 0; j < 4; ++j) acc[i][j] = (f32x4){0.f, 0.f, 0.f, 0.f};

    for (int kt = 0; kt < 8; ++kt) {
      const int k0 = kt << 6;
      __syncthreads();
      #pragma unroll
      for (int c = 0; c < 4; ++c) {
        const int q = c * 256 + tid;
        const int row = q >> 3;
        const int c8 = q & 7;
        const int lc = c8 ^ (row & 7);
        gload_lds16(A  + (size_t)(m0 + row) * 512 + k0 + lc * 8, As + q * 8);
        gload_lds16(Bt + (size_t)(n0 + row) * 512 + k0 + lc * 8, Bs + q * 8);
      }
      __syncthreads();
      const int r = lane & 15;
      const int hi = lane >> 4;
      bf16x8 af[4][2], bfr[4][2];
      #pragma unroll
      for (int i = 0; i < 4; ++i) {
        const int ra = wm + i * 16 + r;
        const int rb = wn + i * 16 + r;
        #pragma unroll
        for (int kk = 0; kk < 2; ++kk) {
          af[i][kk]  = *(const bf16x8*)(As + ra * 64 + (((kk * 4 + hi)) ^ (ra & 7)) * 8);
          bfr[i][kk] = *(const bf16x8*)(Bs + rb * 64 + (((kk * 4 + hi)) ^ (rb & 7)) * 8);
        }
      }
      #pragma unroll
      for (int kk = 0; kk < 2; ++kk)
        #pragma unroll
        for (int i = 0; i < 4; ++i)
          #pragma unroll
          for (int j = 0; j < 4; ++j)
            acc[i][j] = __builtin_amdgcn_mfma_f32_16x16x32_bf16(af[i][kk], bfr[j][kk], acc[i][j], 0, 0, 0);
    }
    const int cl = lane & 15;
    const int rl = (lane >> 4) * 4;
    #pragma unroll
    for (int j = 0; j < 4; ++j) {
      const int col = n0 + wn + j * 16 + cl;
      const float bsv = b_mlp[col];
      #pragma unroll
      for (int i = 0; i < 4; ++i) {
        #pragma unroll
        for (int rr = 0; rr < 4; ++rr) {
          const int row = m0 + wm + i * 16 + rl + rr;
          hbuf[(size_t)row * 512 + col] = m_f32[(size_t)row * 512 + col] + fmaxf(acc[i][j][rr] + bsv, 0.f);
        }
      }
    }
  } else if (bid < 264) {
    float* wtile = (float*)smem;            // 64 KB
    float* vals  = (float*)(smem + 65536);  // 8 KB
    const int g = bid - 8;
    const int s = g >> 5, nc = (g >> 3) & 3, kc = g & 7;
    const int k0 = kc * 64;
    const float* wsrc = W_mg + (size_t)s * 524288 + (size_t)k0 * 1024 + nc * 256;
    #pragma unroll
    for (int i = 0; i < 16; ++i) {
      const int q = i * 256 + tid;          // 4096 chunks of 16B; each wave = one row
      const int row = q >> 6, c16 = q & 63;
      gload_lds16(wsrc + (size_t)row * 1024 + c16 * 4, wtile + q * 4);
    }
    {
      int i = tid * 2;
      int b = i >> 4, k4 = i & 15;
      *(float4*)&vals[b * 64 + k4 * 4] = *(const float4*)&tm[(size_t)(b * 8 + s) * 512 + k0 + k4 * 4];
      i++;
      b = i >> 4; k4 = i & 15;
      *(float4*)&vals[b * 64 + k4 * 4] = *(const float4*)&tm[(size_t)(b * 8 + s) * 512 + k0 + k4 * 4];
    }
    __syncthreads();
    const int col = nc * 256 + tid;
    float acc[32];
    #pragma unroll
    for (int b = 0; b < 32; ++b) acc[b] = 0.f;
    for (int kk = 0; kk < 64; ++kk) {
      float w = wtile[kk * 256 + tid];
      #pragma unroll
      for (int b = 0; b < 32; ++b) acc[b] += vals[b * 64 + kk] * w;
    }
    #pragma unroll
    for (int b = 0; b < 32; ++b)
      gmp[(size_t)((kc * 32 + b) * 8 + s) * 1024 + col] = acc[b];
  } else {
    float* wtile = (float*)smem;
    float* vals  = (float*)(smem + 65536);
    const int j = bid - 264;             // 0..31
    const int nc = j >> 3, kc = j & 7;
    const int k0 = kc * 64;
    const float* wsrc = W_ig + (size_t)k0 * 1024 + nc * 256;
    #pragma unroll
    for (int i = 0; i < 16; ++i) {
      const int q = i * 256 + tid;
      const int row = q >> 6, c16 = q & 63;
      gload_lds16(wsrc + (size_t)row * 1024 + c16 * 4, wtile + q * 4);
    }
    #pragma unroll
    for (int i = 0; i < 8; ++i) {
      const int idx = i * 256 + tid;        // 2048 = 32 b x 64 k
      const int b = idx >> 6, k = idx & 63;
      float a = 0.f;
      #pragma unroll
      for (int ch = 0; ch < 8; ++ch)
        a += gpart[(size_t)(b * 8 + ch) * 512 + k0 + k];
      vals[b * 64 + k] = a * (1.f / 1024.f);
    }
    __syncthreads();
    const int col = nc * 256 + tid;
    float acc[32];
    #pragma unroll
    for (int b = 0; b < 32; ++b) acc[b] = 0.f;
    for (int kk = 0; kk < 64; ++kk) {
      float w = wtile[kk * 256 + tid];
      #pragma unroll
      for (int b = 0; b < 32; ++b) acc[b] += vals[b * 64 + kk] * w;
    }
    const float badd = (kc == 0) ? b_ig[col] : 0.f;
    #pragma unroll
    for (int b = 0; b < 32; ++b)
      gip[(size_t)(kc * 32 + b) * 1024 + col] = acc[b] + badd;
  }
}

// ---------------- kv partials with fused LN2+gating: nmem slice computed in-block ----------------
__global__ __launch_bounds__(256) void k_kvgate(
    const float* __restrict__ hbuf, const float* __restrict__ g2, const float* __restrict__ be2,
    const float* __restrict__ gip, const float* __restrict__ gmp,
    const float* __restrict__ b_mg, const float* __restrict__ memory,
    const float* __restrict__ fbias, const float* __restrict__ ibias,
    const float* __restrict__ Wk, const float* __restrict__ Wv,
    float* __restrict__ kvp)
{
  const int b = blockIdx.x, nc = blockIdx.y, kc = blockIdx.z;
  const int tid = threadIdx.x;
  const int k0 = kc * 128;
  __shared__ float hb[8][512];
  __shared__ float red[2][8][32];
  __shared__ float mus[8], rss[8];
  __shared__ float nm[8][128];
  #pragma unroll
  for (int i = 0; i < 4; ++i) {
    int idx = i * 256 + tid;
    int s = idx >> 7, c4 = idx & 127;
    *(float4*)&hb[s][c4 * 4] = *(const float4*)&hbuf[(size_t)(b * 8 + s) * 512 + c4 * 4];
  }
  __syncthreads();
  {
    int s = tid >> 5, l = tid & 31;
    float sm = 0.f, sq = 0.f;
    #pragma unroll
    for (int j = 0; j < 16; ++j) {
      float v = hb[s][l * 16 + j];
      sm += v; sq += v * v;
    }
    red[0][s][l] = sm; red[1][s][l] = sq;
  }
  __syncthreads();
  if (tid < 8) {
    float sm = 0.f, sq = 0.f;
    #pragma unroll
    for (int l = 0; l < 32; ++l) { sm += red[0][tid][l]; sq += red[1][tid][l]; }
    float mu = sm * (1.f / 512.f);
    float var = sq * (1.f / 512.f) - mu * mu;
    mus[tid] = mu;
    rss[tid] = rsqrtf(var + 1e-5f);
  }
  __syncthreads();
  const float fb = fbias[0], ib = ibias[0];
  #pragma unroll
  for (int i = 0; i < 4; ++i) {
    int idx = i * 256 + tid;
    int s = idx >> 7, ee = idx & 127;
    int e = k0 + ee;
    float ln = (hb[s][e] - mus[s]) * rss[s] * g2[e] + be2[e];
    float gin = b_mg[s * 1024 + e], gfn = b_mg[s * 1024 + 512 + e];
    #pragma unroll
    for (int kc2 = 0; kc2 < 8; ++kc2) {
      size_t gp = (size_t)((kc2 * 32 + b) * 8 + s) * 1024;
      gin += gmp[gp + e];
      gfn += gmp[gp + 512 + e];
    }
    float giv_i = 0.f, giv_f = 0.f;
    #pragma unroll
    for (int kc2 = 0; kc2 < 8; ++kc2) {
      size_t gp = (size_t)(kc2 * 32 + b) * 1024;
      giv_i += gip[gp + e];
      giv_f += gip[gp + 512 + e];
    }
    float ing = 1.f / (1.f + __expf(-(giv_i + gin + ib)));
    float fg  = 1.f / (1.f + __expf(-(giv_f + gfn + fb)));
    nm[s][ee] = ing * tanhf(ln) + fg * memory[(size_t)(b * 8 + s) * 512 + e];
  }
  __syncthreads();
  const int col = tid & 127, rg = tid >> 7;
  const int cg = nc * 128 + col;
  const float* wp; int stride;
  if (nc == 0) { wp = Wk + (size_t)k0 * 128 + cg; stride = 128; }
  else         { wp = Wv + (size_t)k0 * 512 + (cg - 128); stride = 512; }
  const int b0 = rg * 4;
  float a0 = 0.f, a1 = 0.f, a2 = 0.f, a3 = 0.f;
  #pragma unroll 4
  for (int kk = 0; kk < 128; ++kk) {
    float w = wp[(size_t)kk * stride];
    a0 += nm[b0][kk] * w;
    a1 += nm[b0 + 1][kk] * w;
    a2 += nm[b0 + 2][kk] * w;
    a3 += nm[b0 + 3][kk] * w;
  }
  kvp[(size_t)((kc * 32 + b) * 8 + b0    ) * 640 + cg] = a0;
  kvp[(size_t)((kc * 32 + b) * 8 + b0 + 1) * 640 + cg] = a1;
  kvp[(size_t)((kc * 32 + b) * 8 + b0 + 2) * 640 + cg] = a2;
  kvp[(size_t)((kc * 32 + b) * 8 + b0 + 3) * 640 + cg] = a3;
}

// ---------------- final broadcast attention -> out (T,B,E); 16 tokens/block ----------------
__global__ __launch_bounds__(256) void k_out_attn(
    const u16* __restrict__ kq, const float* __restrict__ kvp,
    const float* __restrict__ bk, const float* __restrict__ bv,
    float* __restrict__ out)
{
  int b = blockIdx.x, tc = blockIdx.y;
  int tid = threadIdx.x;
  __shared__ float km[1024];
  __shared__ float vm[4096];
  __shared__ float pr[1024];
  for (int i = tid; i < 1024; i += 256) {
    int s = i >> 7, j = i & 127;
    float a = bk[j];
    #pragma unroll
    for (int kc = 0; kc < 4; ++kc)
      a += kvp[(size_t)((kc * 32 + b) * 8 + s) * 640 + j];
    km[i] = a;
  }
  for (int i = tid; i < 4096; i += 256) {
    int s = i >> 9, c = i & 511;
    float a = bv[c];
    #pragma unroll
    for (int kc = 0; kc < 4; ++kc)
      a += kvp[(size_t)((kc * 32 + b) * 8 + s) * 640 + 128 + c];
    vm[i] = a;
  }
  __syncthreads();
  if (tid < 128) {
    int tt = tid >> 3, hh = tid & 7;
    int t = tc * 16 + tt;
    const u16* qrow = kq + ((size_t)(b * 1024 + t)) * 256 + 128 + hh * 16;
    float q[16];
    #pragma unroll
    for (int d = 0; d < 16; ++d) q[d] = b2f(qrow[d]);
    float s8[8]; float mx = -1e38f;
    #pragma unroll
    for (int s = 0; s < 8; ++s) {
      float a = 0.f;
      #pragma unroll
      for (int d = 0; d < 16; ++d) a += q[d] * km[s * 128 + hh * 16 + d];
      s8[s] = a; mx = fmaxf(mx, a);
    }
    float se = 0.f;
    #pragma unroll
    for (int s = 0; s < 8; ++s) { s8[s] = __expf(s8[s] - mx); se += s8[s]; }
    float inv = 1.f / se;
    #pragma unroll
    for (int s = 0; s < 8; ++s) pr[(tt * 8 + hh) * 8 + s] = s8[s] * inv;
  }
  __syncthreads();
  #pragma unroll
  for (int oi = 0; oi < 8; ++oi) {
    int o = oi * 256 + tid;
    int tt = o >> 7, c4 = o & 127;
    int c = c4 * 4, hh = c >> 6;
    const float* prp = &pr[(tt * 8 + hh) * 8];
    float4 r = {0.f, 0.f, 0.f, 0.f};
    #pragma unroll
    for (int s = 0; s < 8; ++s) {
      float p = prp[s];
      float4 v = *(const float4*)&vm[s * 512 + c];
      r.x += p * v.x; r.y += p * v.y; r.z += p * v.z; r.w += p * v.w;
    }
    int t = tc * 16 + tt;
    *(float4*)&out[((size_t)t * 32 + b) * 512 + c] = r;
  }
}

extern "C" void kernel_launch(void* const* d_in, const int* in_sizes, int n_in,
                              void* d_out, int out_size, void* d_ws, size_t ws_size,
                              hipStream_t stream) {
  (void)in_sizes; (void)n_in; (void)out_size; (void)ws_size;
  const float* key   = (const float*)d_in[1];
  const float* memory= (const float*)d_in[2];
  const float* W_in  = (const float*)d_in[3];
  const float* b_in  = (const float*)d_in[4];
  const float* Wq    = (const float*)d_in[5];
  const float* bq    = (const float*)d_in[6];
  const float* Wk    = (const float*)d_in[7];
  const float* bk    = (const float*)d_in[8];
  const float* Wv    = (const float*)d_in[9];
  const float* bv    = (const float*)d_in[10];
  const float* W_mlp = (const float*)d_in[11];
  const float* b_mlp = (const float*)d_in[12];
  const float* g1    = (const float*)d_in[13];
  const float* be1   = (const float*)d_in[14];
  const float* g2    = (const float*)d_in[15];
  const float* be2   = (const float*)d_in[16];
  const float* w_rep = (const float*)d_in[17];
  const float* W_ig  = (const float*)d_in[18];
  const float* b_ig  = (const float*)d_in[19];
  const float* W_mg  = (const float*)d_in[20];
  const float* b_mg  = (const float*)d_in[21];
  const float* fbias = (const float*)d_in[22];
  const float* ibias = (const float*)d_in[23];
  float* out = (float*)d_out;

  char* p = (char*)d_ws;
  auto alloc = [&](size_t bytes) { char* r = p; p += (bytes + 255) & ~(size_t)255; return r; };
  u16* x       = (u16*)alloc(33554432);    // x bf16 (B*T, 512)
  u16* keyB    = (u16*)alloc(33554432);    // key bf16 (B*T, 512)
  u16* kq      = (u16*)alloc(16777216);    // [k | q] bf16 (B*T, 256)
  u16* WxT     = (u16*)alloc(786432);      // 768 x 512 bf16: [W_in^T ; Wc^T]
  u16* WvT     = (u16*)alloc(524288);
  u16* WkqTr   = (u16*)alloc(262144);
  u16* WinB    = (u16*)alloc(524288);
  u16* WmlpT   = (u16*)alloc(524288);      // W_mlp^T bf16
  float* bfull = (float*)alloc(3072);
  float* gpart = (float*)alloc(524288);    // (B, 8, 512)
  float* gip   = (float*)alloc(1048576);   // (8, B, 1024) partials
  float* gmp   = (float*)alloc(8388608);   // (8, B, S, 1024) partials
  float* att   = (float*)alloc(524288);
  float* m_f32 = (float*)alloc(524288);    // LN1 output f32
  u16*   m_bf  = (u16*)alloc(262144);      // LN1 output bf16
  float* hbuf  = (float*)alloc(524288);    // m + relu(mlp)
  float* kvp   = (float*)alloc(2621440);   // (4, B*8, 640)
  float* tm    = (float*)alloc(524288);
  float* qmw   = (float*)alloc(131072);
  float* p3    = (float*)alloc(32768);
  u16* XW      = (u16*)alloc(2097152);     // (H, 256, 512) bf16

  k_prep<<<13314, 256, 0, stream>>>(W_in, WxT, Wv, WvT, memory, tm, b_in, bfull,
                                    Wk, Wq, WkqTr, WinB, W_mlp, WmlpT, key, keyB);
  k_wprep2<<<41, 256, 0, stream>>>(WkqTr, WinB, WxT, Wq, memory, bq, qmw, b_in, bk, bfull);
  gemm_xkq<<<1536, 256, 0, stream>>>(keyB, WxT, bfull, x, kq);
  k_scores_topk<<<dim3(32, 8, 8), 256, 0, stream>>>(qmw, kq, x, p3, XW);
  k_attgi<<<272, 256, 0, stream>>>(XW, WvT, p3, bv, att, x, w_rep, gpart);
  k_ln1<<<dim3(32, 8), 256, 0, stream>>>(memory, att, g1, be1, m_f32, m_bf);
  k_mlpgigm<<<296, 256, 0, stream>>>(m_bf, WmlpT, b_mlp, m_f32, hbuf,
                                     tm, W_mg, gmp, gpart, W_ig, b_ig, gip);
  k_kvgate<<<dim3(32, 5, 4), 256, 0, stream>>>(hbuf, g2, be2, gip, gmp, b_mg, memory,
                                               fbias, ibias, Wk, Wv, kvp);
  k_out_attn<<<dim3(32, 64), 256, 0, stream>>>(kq, kvp, bk, bv, out);
}